// Round 6
// baseline (23271.735 us; speedup 1.0000x reference)
//
#include <hip/hip_runtime.h>
#include <cstddef>

typedef __attribute__((ext_vector_type(8))) short short8v;   // 8 bf16 = 4 VGPRs
typedef __attribute__((ext_vector_type(4))) float float4v;   // MFMA acc

__device__ __forceinline__ float sigmoidf_(float x) {
    return 1.0f / (1.0f + __expf(-x));
}

__device__ __forceinline__ short f2bf(float f) {   // fp32 -> bf16 (RNE)
    union { float f; unsigned u; } v; v.f = f;
    unsigned r = (v.u + 0x7fffu + ((v.u >> 16) & 1u)) >> 16;
    return (short)r;
}

__device__ __forceinline__ float bfhi2f(unsigned bits_in_high) {  // bf16 bits at [31:16]
    union { unsigned u; float f; } v; v.u = bits_in_high; return v.f;
}

__device__ __forceinline__ short8v pack8(float4 a, float4 b) {
    short8v r;
    r[0] = f2bf(a.x); r[1] = f2bf(a.y); r[2] = f2bf(a.z); r[3] = f2bf(a.w);
    r[4] = f2bf(b.x); r[5] = f2bf(b.y); r[6] = f2bf(b.z); r[7] = f2bf(b.w);
    return r;
}

#define FMA4(a4, w, x) \
    do { a4.x += (w).x*(x).x; a4.y += (w).y*(x).y; a4.z += (w).z*(x).z; a4.w += (w).w*(x).w; } while (0)

// ---------------- Prenet ----------------
__global__ __launch_bounds__(256) void prenet_kernel(
    const float* __restrict__ y_mels,   // [B][T][80]
    const float* __restrict__ W1,       // [256][80]
    const float* __restrict__ W2,       // [256][256]
    float* __restrict__ p2,             // [T][B][256]
    int T)
{
    const int rt = blockIdx.x;           // t*32 + b
    const int t = rt >> 5, b = rt & 31;
    const int j = threadIdx.x;           // 0..255
    __shared__ float prev[80];
    __shared__ float p1[256];
    if (j < 80) prev[j] = (t == 0) ? 0.0f : y_mels[((size_t)b * T + (t - 1)) * 80 + j];
    __syncthreads();
    float acc = 0.0f;
    const float* w1r = W1 + j * 80;
    #pragma unroll
    for (int k = 0; k < 80; k += 4) {
        float4 w = *(const float4*)(w1r + k);
        float4 x = *(const float4*)(&prev[k]);
        acc += w.x * x.x + w.y * x.y + w.z * x.z + w.w * x.w;
    }
    p1[j] = fmaxf(acc, 0.0f);
    __syncthreads();
    float4 a4 = make_float4(0.f, 0.f, 0.f, 0.f);
    const float* w2r = W2 + j * 256;
    #pragma unroll 8
    for (int k = 0; k < 256; k += 4) {
        float4 w = *(const float4*)(w2r + k);
        float4 x = *(const float4*)(&p1[k]);
        FMA4(a4, w, x);
    }
    p2[(size_t)rt * 256 + j] = fmaxf((a4.x + a4.y) + (a4.z + a4.w), 0.0f);
}

// ------------- Projection, memory part -------------
__global__ __launch_bounds__(128) void proj_mem_kernel(
    const float* __restrict__ memory, // [B][T][512]
    const float* __restrict__ Wp,     // [80][1536]
    const float* __restrict__ bp,     // [80]
    float* __restrict__ out,          // [B][T][80]
    int T)
{
    const int rt = blockIdx.x;
    const int tid = threadIdx.x;
    __shared__ float xm[512];
    for (int k = tid * 4; k < 512; k += 128 * 4)
        *(float4*)(&xm[k]) = *(const float4*)(memory + (size_t)rt * 512 + k);
    __syncthreads();
    if (tid < 80) {
        const float* wr = Wp + tid * 1536 + 1024;
        float4 a4 = make_float4(0.f, 0.f, 0.f, 0.f);
        #pragma unroll 8
        for (int k = 0; k < 512; k += 4) {
            float4 w = *(const float4*)(wr + k);
            float4 x = *(const float4*)(&xm[k]);
            FMA4(a4, w, x);
        }
        out[(size_t)rt * 80 + tid] = bp[tid] + (a4.x + a4.y) + (a4.z + a4.w);
    }
}

// ================= Persistent-weight MFMA scan, fan-out barrier =================
// 256 blocks x 512 threads. Work decomposition as round 4/5. Barrier: 16 group
// counters -> root -> 16 notify lines (epoch broadcast); spinners poll only
// their group's notify line with s_sleep backoff.
// bar dword layout: [g*16] group counters (g<16), [256] root, [512+g*16] notify.
__global__ __launch_bounds__(512, 2) void fused_scan_mfma(
    const float* __restrict__ p2,     // [T][B][256]
    const float* __restrict__ memory, // [B][T][512]
    const float* __restrict__ w_ih0,  // [4096][768]
    const float* __restrict__ w_hh0,  // [4096][1024]
    const float* __restrict__ b_ih0,
    const float* __restrict__ b_hh0,
    const float* __restrict__ w_ih1,  // [4096][1024]
    const float* __restrict__ w_hh1,  // [4096][1024]
    const float* __restrict__ b_ih1,
    const float* __restrict__ b_hh1,
    const float* __restrict__ Wp,     // [80][1536]
    unsigned short* __restrict__ hb0, // [2][32][1024] bf16 (memset 0)
    unsigned short* __restrict__ hb1, // [4][32][1024] bf16 (memset 0)
    float* __restrict__ out,          // [B][T][80] (pre-filled with mem part)
    unsigned* __restrict__ bar,       // barrier state (memset 0)
    int T)
{
    const int bk  = blockIdx.x;
    const int tid = threadIdx.x;
    const int wave = tid >> 6;
    const int lane = tid & 63;
    const int col  = lane & 15;          // MFMA col (n) / A row (m)
    const int oct  = (lane >> 4) & 3;    // k-octet selector
    const int jcol = ((col >> 2) * 1024) + bk * 4 + (col & 3);

    // ---- persistent weight fragments ----
    const float* wr_i0 = w_ih0 + (size_t)jcol * 768;
    const float* wr_h0 = w_hh0 + (size_t)jcol * 1024;
    const float* wr_i1 = w_ih1 + (size_t)jcol * 1024;
    const float* wr_h1 = w_hh1 + (size_t)jcol * 1024;
    short8v wf_i0[3], wf_h0[4], wf_i1[4], wf_h1[4];
    #pragma unroll
    for (int s = 0; s < 3; ++s) {
        int k = wave * 96 + s * 32 + oct * 8;
        wf_i0[s] = pack8(*(const float4*)(wr_i0 + k), *(const float4*)(wr_i0 + k + 4));
    }
    #pragma unroll
    for (int s = 0; s < 4; ++s) {
        int k = wave * 128 + s * 32 + oct * 8;
        wf_h0[s] = pack8(*(const float4*)(wr_h0 + k), *(const float4*)(wr_h0 + k + 4));
        wf_i1[s] = pack8(*(const float4*)(wr_i1 + k), *(const float4*)(wr_i1 + k + 4));
        wf_h1[s] = pack8(*(const float4*)(wr_h1 + k), *(const float4*)(wr_h1 + k + 4));
    }

    // ---- LDS ----
    __shared__ float red[8][4][16][17];   // padded: +1 breaks 4-oct bank aliasing
    __shared__ float gl2[2][32][16];
    __shared__ float cst[2][32][4];
    __shared__ float bias_l[2][16];
    if (tid < 32) {
        int ly = tid >> 4, jl = tid & 15;
        int j = ((jl >> 2) * 1024) + bk * 4 + (jl & 3);
        bias_l[ly][jl] = ly ? (b_ih1[j] + b_hh1[j]) : (b_ih0[j] + b_hh0[j]);
    }
    if (tid < 256) cst[tid >> 7][(tid >> 2) & 31][tid & 3] = 0.0f;

    // ---- persistent projection weights ----
    const int gid = bk * 16 + (tid >> 5);
    const int lane32 = tid & 31;
    const int pb = gid / 80, po = gid - pb * 80;
    float wp[32];
    if (gid < 2560) {
        #pragma unroll
        for (int i = 0; i < 8; ++i) {
            float4 w = *(const float4*)(Wp + (size_t)po * 1536 + lane32 * 4 + i * 128);
            wp[i*4+0] = w.x; wp[i*4+1] = w.y; wp[i*4+2] = w.z; wp[i*4+3] = w.w;
        }
    }

    unsigned* grp_cnt   = bar + (bk >> 4) * 16;
    unsigned* root_cnt  = bar + 256;
    unsigned* notify    = bar + 512;
    unsigned* my_notify = notify + (bk >> 4) * 16;

    // ---- input GEMM lambda (x = [p2 | memory], K=768) ----
    auto input_gemm = [&](int tt, float4v* acc) {
        #pragma unroll
        for (int s = 0; s < 3; ++s) {
            int kb = wave * 96 + s * 32;
            int kk = kb + oct * 8;
            short8v a0, a1;
            if (kb < 256) {
                const float* s0 = p2 + ((size_t)tt * 32 + col) * 256 + kk;
                const float* s1 = p2 + ((size_t)tt * 32 + col + 16) * 256 + kk;
                a0 = pack8(*(const float4*)s0, *(const float4*)(s0 + 4));
                a1 = pack8(*(const float4*)s1, *(const float4*)(s1 + 4));
            } else {
                const float* s0 = memory + ((size_t)col * T + tt) * 512 + (kk - 256);
                const float* s1 = memory + ((size_t)(col + 16) * T + tt) * 512 + (kk - 256);
                a0 = pack8(*(const float4*)s0, *(const float4*)(s0 + 4));
                a1 = pack8(*(const float4*)s1, *(const float4*)(s1 + 4));
            }
            acc[0] = __builtin_amdgcn_mfma_f32_16x16x32_bf16(a0, wf_i0[s], acc[0], 0, 0, 0);
            acc[1] = __builtin_amdgcn_mfma_f32_16x16x32_bf16(a1, wf_i0[s], acc[1], 0, 0, 0);
        }
    };

    __syncthreads();

    // prologue: input GEMM for t=0 (p2 ready by stream order)
    float4v acc0[2];
    acc0[0] = (float4v){0.f, 0.f, 0.f, 0.f};
    acc0[1] = (float4v){0.f, 0.f, 0.f, 0.f};
    if (T > 0) input_gemm(0, acc0);

    for (int t = 0; t <= T + 1; ++t) {
        // ---- wait for epoch t (barrier of phase t-1) ----
        if (t > 0) {
            if (tid == 0) {
                while (__hip_atomic_load(my_notify, __ATOMIC_RELAXED,
                                         __HIP_MEMORY_SCOPE_AGENT) < (unsigned)t)
                    __builtin_amdgcn_s_sleep(1);
                (void)__hip_atomic_load(my_notify, __ATOMIC_ACQUIRE,
                                        __HIP_MEMORY_SCOPE_AGENT);
            }
            __syncthreads();
        }

        const bool doL0 = (t < T);
        const bool doL1 = (t >= 1) && (t <= T);
        float4v acc1[2];
        acc1[0] = (float4v){0.f, 0.f, 0.f, 0.f};
        acc1[1] = (float4v){0.f, 0.f, 0.f, 0.f};
        const unsigned short* h0prev  = hb0 + (size_t)((t + 1) & 1) * 32768;   // h0[t-1]
        const unsigned short* h1prev2 = hb1 + (size_t)((t - 2) & 3) * 32768;   // h1[t-2]

        // ---- h0[t-1]-driven GEMMs ----
        if (doL0 || doL1) {
            #pragma unroll
            for (int s = 0; s < 4; ++s) {
                int kk = wave * 128 + s * 32 + oct * 8;
                short8v a0 = *(const short8v*)(h0prev + (size_t)col * 1024 + kk);
                short8v a1 = *(const short8v*)(h0prev + (size_t)(col + 16) * 1024 + kk);
                if (doL0) {
                    acc0[0] = __builtin_amdgcn_mfma_f32_16x16x32_bf16(a0, wf_h0[s], acc0[0], 0, 0, 0);
                    acc0[1] = __builtin_amdgcn_mfma_f32_16x16x32_bf16(a1, wf_h0[s], acc0[1], 0, 0, 0);
                }
                if (doL1) {
                    acc1[0] = __builtin_amdgcn_mfma_f32_16x16x32_bf16(a0, wf_i1[s], acc1[0], 0, 0, 0);
                    acc1[1] = __builtin_amdgcn_mfma_f32_16x16x32_bf16(a1, wf_i1[s], acc1[1], 0, 0, 0);
                }
            }
            if (doL1) {
                #pragma unroll
                for (int s = 0; s < 4; ++s) {
                    int kk = wave * 128 + s * 32 + oct * 8;
                    short8v a0 = *(const short8v*)(h1prev2 + (size_t)col * 1024 + kk);
                    short8v a1 = *(const short8v*)(h1prev2 + (size_t)(col + 16) * 1024 + kk);
                    acc1[0] = __builtin_amdgcn_mfma_f32_16x16x32_bf16(a0, wf_h1[s], acc1[0], 0, 0, 0);
                    acc1[1] = __builtin_amdgcn_mfma_f32_16x16x32_bf16(a1, wf_h1[s], acc1[1], 0, 0, 0);
                }
            }
        }
        // ---- cross-wave k-reduction ----
        if (doL0) {
            #pragma unroll
            for (int mt = 0; mt < 2; ++mt)
                #pragma unroll
                for (int r = 0; r < 4; ++r)
                    red[wave][mt][oct * 4 + r][col] = acc0[mt][r];
        }
        if (doL1) {
            #pragma unroll
            for (int mt = 0; mt < 2; ++mt)
                #pragma unroll
                for (int r = 0; r < 4; ++r)
                    red[wave][2 + mt][oct * 4 + r][col] = acc1[mt][r];
        }
        __syncthreads();
        #pragma unroll
        for (int e = tid; e < 1024; e += 512) {
            int tt = e >> 8, m = (e >> 4) & 15, n = e & 15;
            int ly = tt >> 1;
            if (ly ? doL1 : doL0) {
                float s = 0.f;
                #pragma unroll
                for (int w = 0; w < 8; ++w) s += red[w][tt][m][n];
                gl2[ly][(tt & 1) * 16 + m][n] = s + bias_l[ly][n];
            }
        }
        __syncthreads();
        // ---- activations ----
        if (tid < 256) {
            int ly = tid >> 7, rem = tid & 127, bb = rem >> 2, cl = rem & 3;
            if (ly ? doL1 : doL0) {
                float gi = gl2[ly][bb][cl];
                float gf = gl2[ly][bb][4 + cl];
                float gg = gl2[ly][bb][8 + cl];
                float go = gl2[ly][bb][12 + cl];
                float c = sigmoidf_(gf) * cst[ly][bb][cl] + sigmoidf_(gi) * tanhf(gg);
                float h = sigmoidf_(go) * tanhf(c);
                cst[ly][bb][cl] = c;
                unsigned short hv = (unsigned short)f2bf(h);
                if (ly == 0) hb0[(size_t)(t & 1) * 32768 + bb * 1024 + bk * 4 + cl] = hv;           // h0[t]
                else         hb1[(size_t)((t - 1) & 3) * 32768 + bb * 1024 + bk * 4 + cl] = hv;     // h1[t-1]
            }
        }
        __syncthreads();   // drain h stores before publishing

        // ---- arrive(epoch t+1): group -> root -> broadcast to 16 notify lines ----
        if (tid == 0) {
            unsigned old = __hip_atomic_fetch_add(grp_cnt, 1u, __ATOMIC_ACQ_REL,
                                                  __HIP_MEMORY_SCOPE_AGENT);
            if (old == 16u * (unsigned)(t + 1) - 1u) {
                unsigned rold = __hip_atomic_fetch_add(root_cnt, 1u, __ATOMIC_ACQ_REL,
                                                       __HIP_MEMORY_SCOPE_AGENT);
                if (rold == 16u * (unsigned)(t + 1) - 1u) {
                    #pragma unroll
                    for (int g = 0; g < 16; ++g)
                        __hip_atomic_store(notify + g * 16, (unsigned)(t + 1),
                                           __ATOMIC_RELEASE, __HIP_MEMORY_SCOPE_AGENT);
                }
            }
        }

        // ---- window: independent work overlapping barrier propagation ----
        if (t >= 2 && gid < 2560) {
            const unsigned short* hrow = h1prev2 + (size_t)pb * 1024;
            float sum = 0.f;
            #pragma unroll
            for (int i = 0; i < 8; ++i) {
                int k = lane32 * 4 + i * 128;
                uint2 hv = *(const uint2*)(hrow + k);
                float x0 = bfhi2f(hv.x << 16);
                float x1 = bfhi2f(hv.x & 0xffff0000u);
                float x2 = bfhi2f(hv.y << 16);
                float x3 = bfhi2f(hv.y & 0xffff0000u);
                sum += wp[i*4+0]*x0 + wp[i*4+1]*x1 + wp[i*4+2]*x2 + wp[i*4+3]*x3;
            }
            sum += __shfl_xor(sum, 16);
            sum += __shfl_xor(sum, 8);
            sum += __shfl_xor(sum, 4);
            sum += __shfl_xor(sum, 2);
            sum += __shfl_xor(sum, 1);
            if (lane32 == 0) {
                float* op = out + ((size_t)pb * T + (t - 2)) * 80 + po;
                *op += sum;
            }
        }
        // next step's input GEMM (read-only inputs)
        acc0[0] = (float4v){0.f, 0.f, 0.f, 0.f};
        acc0[1] = (float4v){0.f, 0.f, 0.f, 0.f};
        if (t + 1 < T) input_gemm(t + 1, acc0);
    }
}

extern "C" void kernel_launch(void* const* d_in, const int* in_sizes, int n_in,
                              void* d_out, int out_size, void* d_ws, size_t ws_size,
                              hipStream_t stream)
{
    const float* memory = (const float*)d_in[0];   // [32][1000][512]
    const float* y_mels = (const float*)d_in[1];   // [32][1000][80]
    const float* W1     = (const float*)d_in[2];   // [256][80]
    const float* W2     = (const float*)d_in[3];   // [256][256]
    const float* w_ih0  = (const float*)d_in[4];   // [4096][768]
    const float* w_hh0  = (const float*)d_in[5];   // [4096][1024]
    const float* b_ih0  = (const float*)d_in[6];
    const float* b_hh0  = (const float*)d_in[7];
    const float* w_ih1  = (const float*)d_in[8];   // [4096][1024]
    const float* w_hh1  = (const float*)d_in[9];   // [4096][1024]
    const float* b_ih1  = (const float*)d_in[10];
    const float* b_hh1  = (const float*)d_in[11];
    const float* Wp     = (const float*)d_in[12];  // [80][1536]
    const float* bp     = (const float*)d_in[13];  // [80]
    float* out = (float*)d_out;

    const int B = 32, T = 1000;

    float* ws = (float*)d_ws;
    float* p2 = ws;                                               // [T][B][256] fp32
    unsigned short* hb0 = (unsigned short*)(p2 + (size_t)T * B * 256); // [2][32][1024] bf16
    unsigned short* hb1 = hb0 + 2 * 32 * 1024;                         // [4][32][1024] bf16
    unsigned* bar = (unsigned*)(hb1 + 4 * 32 * 1024);                  // 16 KB barrier state

    // zero h buffers + barrier state (d_ws is poisoned 0xAA before every launch)
    hipMemsetAsync(hb0, 0,
                   (size_t)(2 + 4) * 32 * 1024 * sizeof(unsigned short) + 16384, stream);

    prenet_kernel<<<T * B, 256, 0, stream>>>(y_mels, W1, W2, p2, T);
    proj_mem_kernel<<<B * T, 128, 0, stream>>>(memory, Wp, bp, out, T);

    {
        int Tt = T;
        void* args[] = { (void*)&p2, (void*)&memory,
                         (void*)&w_ih0, (void*)&w_hh0, (void*)&b_ih0, (void*)&b_hh0,
                         (void*)&w_ih1, (void*)&w_hh1, (void*)&b_ih1, (void*)&b_hh1,
                         (void*)&Wp, (void*)&hb0, (void*)&hb1, (void*)&out, (void*)&bar, (void*)&Tt };
        hipLaunchCooperativeKernel((void*)fused_scan_mfma, dim3(256), dim3(512), args, 0, stream);
    }
}

// Round 7
// 19669.122 us; speedup vs baseline: 1.1832x; 1.1832x over previous
//
#include <hip/hip_runtime.h>
#include <cstddef>

typedef __attribute__((ext_vector_type(8))) short short8v;   // 8 bf16 = 4 VGPRs
typedef __attribute__((ext_vector_type(4))) float float4v;   // MFMA acc
typedef unsigned long long u64;

__device__ __forceinline__ float sigmoidf_(float x) {
    return 1.0f / (1.0f + __expf(-x));
}

__device__ __forceinline__ short f2bf(float f) {   // fp32 -> bf16 (RNE)
    union { float f; unsigned u; } v; v.f = f;
    unsigned r = (v.u + 0x7fffu + ((v.u >> 16) & 1u)) >> 16;
    return (short)r;
}

__device__ __forceinline__ float bfhi2f(unsigned bits_in_high) {  // bf16 bits at [31:16]
    union { unsigned u; float f; } v; v.u = bits_in_high; return v.f;
}

__device__ __forceinline__ short8v pack8(float4 a, float4 b) {
    short8v r;
    r[0] = f2bf(a.x); r[1] = f2bf(a.y); r[2] = f2bf(a.z); r[3] = f2bf(a.w);
    r[4] = f2bf(b.x); r[5] = f2bf(b.y); r[6] = f2bf(b.z); r[7] = f2bf(b.w);
    return r;
}

// coherent (agent-scope, L2-bypassing) 16B h-fragment load as two 8B atomics
__device__ __forceinline__ short8v load_h16(const unsigned short* p) {
    union { u64 q[2]; short8v v; } u;
    u.q[0] = __hip_atomic_load((const u64*)p,       __ATOMIC_RELAXED, __HIP_MEMORY_SCOPE_AGENT);
    u.q[1] = __hip_atomic_load((const u64*)(p + 4), __ATOMIC_RELAXED, __HIP_MEMORY_SCOPE_AGENT);
    return u.v;
}

#define FMA4(a4, w, x) \
    do { a4.x += (w).x*(x).x; a4.y += (w).y*(x).y; a4.z += (w).z*(x).z; a4.w += (w).w*(x).w; } while (0)

// ---------------- Prenet ----------------
__global__ __launch_bounds__(256) void prenet_kernel(
    const float* __restrict__ y_mels,   // [B][T][80]
    const float* __restrict__ W1,       // [256][80]
    const float* __restrict__ W2,       // [256][256]
    float* __restrict__ p2,             // [T][B][256]
    int T)
{
    const int rt = blockIdx.x;           // t*32 + b
    const int t = rt >> 5, b = rt & 31;
    const int j = threadIdx.x;           // 0..255
    __shared__ float prev[80];
    __shared__ float p1[256];
    if (j < 80) prev[j] = (t == 0) ? 0.0f : y_mels[((size_t)b * T + (t - 1)) * 80 + j];
    __syncthreads();
    float acc = 0.0f;
    const float* w1r = W1 + j * 80;
    #pragma unroll
    for (int k = 0; k < 80; k += 4) {
        float4 w = *(const float4*)(w1r + k);
        float4 x = *(const float4*)(&prev[k]);
        acc += w.x * x.x + w.y * x.y + w.z * x.z + w.w * x.w;
    }
    p1[j] = fmaxf(acc, 0.0f);
    __syncthreads();
    float4 a4 = make_float4(0.f, 0.f, 0.f, 0.f);
    const float* w2r = W2 + j * 256;
    #pragma unroll 8
    for (int k = 0; k < 256; k += 4) {
        float4 w = *(const float4*)(w2r + k);
        float4 x = *(const float4*)(&p1[k]);
        FMA4(a4, w, x);
    }
    p2[(size_t)rt * 256 + j] = fmaxf((a4.x + a4.y) + (a4.z + a4.w), 0.0f);
}

// ------------- Projection, memory part -------------
__global__ __launch_bounds__(128) void proj_mem_kernel(
    const float* __restrict__ memory, // [B][T][512]
    const float* __restrict__ Wp,     // [80][1536]
    const float* __restrict__ bp,     // [80]
    float* __restrict__ out,          // [B][T][80]
    int T)
{
    const int rt = blockIdx.x;
    const int tid = threadIdx.x;
    __shared__ float xm[512];
    for (int k = tid * 4; k < 512; k += 128 * 4)
        *(float4*)(&xm[k]) = *(const float4*)(memory + (size_t)rt * 512 + k);
    __syncthreads();
    if (tid < 80) {
        const float* wr = Wp + tid * 1536 + 1024;
        float4 a4 = make_float4(0.f, 0.f, 0.f, 0.f);
        #pragma unroll 8
        for (int k = 0; k < 512; k += 4) {
            float4 w = *(const float4*)(wr + k);
            float4 x = *(const float4*)(&xm[k]);
            FMA4(a4, w, x);
        }
        out[(size_t)rt * 80 + tid] = bp[tid] + (a4.x + a4.y) + (a4.z + a4.w);
    }
}

// ================= Persistent-weight MFMA scan =================
// 256 blocks x 512 threads, round-5 structure. h exchange uses agent-scope
// RELAXED atomics (per-access LLC coherence, L2 bypass) so the barrier wait
// needs NO acquire -> no per-step L2 bulk invalidate; read-only inputs stay
// L2-cached across steps. Barrier: 16 group counters -> root; spin on root.
__global__ __launch_bounds__(512, 2) void fused_scan_mfma(
    const float* __restrict__ p2,     // [T][B][256]
    const float* __restrict__ memory, // [B][T][512]
    const float* __restrict__ w_ih0,  // [4096][768]
    const float* __restrict__ w_hh0,  // [4096][1024]
    const float* __restrict__ b_ih0,
    const float* __restrict__ b_hh0,
    const float* __restrict__ w_ih1,  // [4096][1024]
    const float* __restrict__ w_hh1,  // [4096][1024]
    const float* __restrict__ b_ih1,
    const float* __restrict__ b_hh1,
    const float* __restrict__ Wp,     // [80][1536]
    unsigned short* __restrict__ hb0, // [2][32][1024] bf16 (memset 0)
    unsigned short* __restrict__ hb1, // [4][32][1024] bf16 (memset 0)
    float* __restrict__ out,          // [B][T][80] (pre-filled with mem part)
    unsigned* __restrict__ bar,       // barrier state (memset 0)
    int T)
{
    const int bk  = blockIdx.x;
    const int tid = threadIdx.x;
    const int wave = tid >> 6;
    const int lane = tid & 63;
    const int col  = lane & 15;          // MFMA col (n) / A row (m)
    const int oct  = (lane >> 4) & 3;    // k-octet selector
    const int jcol = ((col >> 2) * 1024) + bk * 4 + (col & 3);

    // ---- persistent weight fragments ----
    const float* wr_i0 = w_ih0 + (size_t)jcol * 768;
    const float* wr_h0 = w_hh0 + (size_t)jcol * 1024;
    const float* wr_i1 = w_ih1 + (size_t)jcol * 1024;
    const float* wr_h1 = w_hh1 + (size_t)jcol * 1024;
    short8v wf_i0[3], wf_h0[4], wf_i1[4], wf_h1[4];
    #pragma unroll
    for (int s = 0; s < 3; ++s) {
        int k = wave * 96 + s * 32 + oct * 8;
        wf_i0[s] = pack8(*(const float4*)(wr_i0 + k), *(const float4*)(wr_i0 + k + 4));
    }
    #pragma unroll
    for (int s = 0; s < 4; ++s) {
        int k = wave * 128 + s * 32 + oct * 8;
        wf_h0[s] = pack8(*(const float4*)(wr_h0 + k), *(const float4*)(wr_h0 + k + 4));
        wf_i1[s] = pack8(*(const float4*)(wr_i1 + k), *(const float4*)(wr_i1 + k + 4));
        wf_h1[s] = pack8(*(const float4*)(wr_h1 + k), *(const float4*)(wr_h1 + k + 4));
    }

    // ---- LDS ----
    __shared__ float red[8][4][16][16];
    __shared__ float gl2[2][32][16];
    __shared__ float cst[2][32][4];
    __shared__ float bias_l[2][16];
    if (tid < 32) {
        int ly = tid >> 4, jl = tid & 15;
        int j = ((jl >> 2) * 1024) + bk * 4 + (jl & 3);
        bias_l[ly][jl] = ly ? (b_ih1[j] + b_hh1[j]) : (b_ih0[j] + b_hh0[j]);
    }
    if (tid < 256) cst[tid >> 7][(tid >> 2) & 31][tid & 3] = 0.0f;

    // ---- persistent projection weights ----
    const int gid = bk * 16 + (tid >> 5);
    const int lane32 = tid & 31;
    const int pb = gid / 80, po = gid - pb * 80;
    float wp[32];
    if (gid < 2560) {
        #pragma unroll
        for (int i = 0; i < 8; ++i) {
            float4 w = *(const float4*)(Wp + (size_t)po * 1536 + lane32 * 4 + i * 128);
            wp[i*4+0] = w.x; wp[i*4+1] = w.y; wp[i*4+2] = w.z; wp[i*4+3] = w.w;
        }
    }

    unsigned* grp_cnt  = bar + (bk >> 4) * 64;
    unsigned* root_cnt = bar + 1024;

    // ---- input GEMM lambda (x = [p2 | memory], K=768; normal cached loads) ----
    auto input_gemm = [&](int tt, float4v* acc) {
        #pragma unroll
        for (int s = 0; s < 3; ++s) {
            int kb = wave * 96 + s * 32;
            int kk = kb + oct * 8;
            short8v a0, a1;
            if (kb < 256) {
                const float* s0 = p2 + ((size_t)tt * 32 + col) * 256 + kk;
                const float* s1 = p2 + ((size_t)tt * 32 + col + 16) * 256 + kk;
                a0 = pack8(*(const float4*)s0, *(const float4*)(s0 + 4));
                a1 = pack8(*(const float4*)s1, *(const float4*)(s1 + 4));
            } else {
                const float* s0 = memory + ((size_t)col * T + tt) * 512 + (kk - 256);
                const float* s1 = memory + ((size_t)(col + 16) * T + tt) * 512 + (kk - 256);
                a0 = pack8(*(const float4*)s0, *(const float4*)(s0 + 4));
                a1 = pack8(*(const float4*)s1, *(const float4*)(s1 + 4));
            }
            acc[0] = __builtin_amdgcn_mfma_f32_16x16x32_bf16(a0, wf_i0[s], acc[0], 0, 0, 0);
            acc[1] = __builtin_amdgcn_mfma_f32_16x16x32_bf16(a1, wf_i0[s], acc[1], 0, 0, 0);
        }
    };

    __syncthreads();

    // prologue: input GEMM for t=0 (p2 ready by stream order)
    float4v acc0[2];
    acc0[0] = (float4v){0.f, 0.f, 0.f, 0.f};
    acc0[1] = (float4v){0.f, 0.f, 0.f, 0.f};
    if (T > 0) input_gemm(0, acc0);

    for (int t = 0; t <= T + 1; ++t) {
        // ---- wait for barrier t-1 (no acquire: h is per-access coherent) ----
        if (t > 0) {
            if (tid == 0) {
                while (__hip_atomic_load(root_cnt, __ATOMIC_RELAXED, __HIP_MEMORY_SCOPE_AGENT)
                       < 16u * (unsigned)t) { }
            }
            __syncthreads();
        }

        const bool doL0 = (t < T);
        const bool doL1 = (t >= 1) && (t <= T);
        float4v acc1[2];
        acc1[0] = (float4v){0.f, 0.f, 0.f, 0.f};
        acc1[1] = (float4v){0.f, 0.f, 0.f, 0.f};
        const unsigned short* h0prev  = hb0 + (size_t)((t + 1) & 1) * 32768;   // h0[t-1]
        const unsigned short* h1prev2 = hb1 + (size_t)((t - 2) & 3) * 32768;   // h1[t-2]

        // ---- h0[t-1]-driven GEMMs (coherent loads) ----
        if (doL0 || doL1) {
            #pragma unroll
            for (int s = 0; s < 4; ++s) {
                int kk = wave * 128 + s * 32 + oct * 8;
                short8v a0 = load_h16(h0prev + (size_t)col * 1024 + kk);
                short8v a1 = load_h16(h0prev + (size_t)(col + 16) * 1024 + kk);
                if (doL0) {
                    acc0[0] = __builtin_amdgcn_mfma_f32_16x16x32_bf16(a0, wf_h0[s], acc0[0], 0, 0, 0);
                    acc0[1] = __builtin_amdgcn_mfma_f32_16x16x32_bf16(a1, wf_h0[s], acc0[1], 0, 0, 0);
                }
                if (doL1) {
                    acc1[0] = __builtin_amdgcn_mfma_f32_16x16x32_bf16(a0, wf_i1[s], acc1[0], 0, 0, 0);
                    acc1[1] = __builtin_amdgcn_mfma_f32_16x16x32_bf16(a1, wf_i1[s], acc1[1], 0, 0, 0);
                }
            }
            if (doL1) {
                #pragma unroll
                for (int s = 0; s < 4; ++s) {
                    int kk = wave * 128 + s * 32 + oct * 8;
                    short8v a0 = load_h16(h1prev2 + (size_t)col * 1024 + kk);
                    short8v a1 = load_h16(h1prev2 + (size_t)(col + 16) * 1024 + kk);
                    acc1[0] = __builtin_amdgcn_mfma_f32_16x16x32_bf16(a0, wf_h1[s], acc1[0], 0, 0, 0);
                    acc1[1] = __builtin_amdgcn_mfma_f32_16x16x32_bf16(a1, wf_h1[s], acc1[1], 0, 0, 0);
                }
            }
        }
        // ---- cross-wave k-reduction ----
        if (doL0) {
            #pragma unroll
            for (int mt = 0; mt < 2; ++mt)
                #pragma unroll
                for (int r = 0; r < 4; ++r)
                    red[wave][mt][oct * 4 + r][col] = acc0[mt][r];
        }
        if (doL1) {
            #pragma unroll
            for (int mt = 0; mt < 2; ++mt)
                #pragma unroll
                for (int r = 0; r < 4; ++r)
                    red[wave][2 + mt][oct * 4 + r][col] = acc1[mt][r];
        }
        __syncthreads();
        #pragma unroll
        for (int e = tid; e < 1024; e += 512) {
            int tt = e >> 8, m = (e >> 4) & 15, n = e & 15;
            int ly = tt >> 1;
            if (ly ? doL1 : doL0) {
                float s = 0.f;
                #pragma unroll
                for (int w = 0; w < 8; ++w) s += red[w][tt][m][n];
                gl2[ly][(tt & 1) * 16 + m][n] = s + bias_l[ly][n];
            }
        }
        __syncthreads();
        // ---- activations (coherent 2B h stores) ----
        if (tid < 256) {
            int ly = tid >> 7, rem = tid & 127, bb = rem >> 2, cl = rem & 3;
            if (ly ? doL1 : doL0) {
                float gi = gl2[ly][bb][cl];
                float gf = gl2[ly][bb][4 + cl];
                float gg = gl2[ly][bb][8 + cl];
                float go = gl2[ly][bb][12 + cl];
                float c = sigmoidf_(gf) * cst[ly][bb][cl] + sigmoidf_(gi) * tanhf(gg);
                float h = sigmoidf_(go) * tanhf(c);
                cst[ly][bb][cl] = c;
                unsigned short hv = (unsigned short)f2bf(h);
                if (ly == 0)
                    __hip_atomic_store(hb0 + (size_t)(t & 1) * 32768 + bb * 1024 + bk * 4 + cl,
                                       hv, __ATOMIC_RELAXED, __HIP_MEMORY_SCOPE_AGENT);      // h0[t]
                else
                    __hip_atomic_store(hb1 + (size_t)((t - 1) & 3) * 32768 + bb * 1024 + bk * 4 + cl,
                                       hv, __ATOMIC_RELAXED, __HIP_MEMORY_SCOPE_AGENT);      // h1[t-1]
            }
        }
        __syncthreads();   // drains vmcnt: h stores complete before arrive

        // ---- arrive(t): group -> root (release publishes our stores' order) ----
        if (tid == 0) {
            unsigned old = __hip_atomic_fetch_add(grp_cnt, 1u, __ATOMIC_ACQ_REL,
                                                  __HIP_MEMORY_SCOPE_AGENT);
            if (old == 16u * (unsigned)(t + 1) - 1u)
                __hip_atomic_fetch_add(root_cnt, 1u, __ATOMIC_ACQ_REL,
                                       __HIP_MEMORY_SCOPE_AGENT);
        }

        // ---- window: independent work overlapping barrier propagation ----
        if (t >= 2 && gid < 2560) {
            const unsigned short* hrow = h1prev2 + (size_t)pb * 1024;
            float sum = 0.f;
            #pragma unroll
            for (int i = 0; i < 8; ++i) {
                int k = lane32 * 4 + i * 128;
                u64 q = __hip_atomic_load((const u64*)(hrow + k),
                                          __ATOMIC_RELAXED, __HIP_MEMORY_SCOPE_AGENT);
                float x0 = bfhi2f(((unsigned)(q       & 0xffffu)) << 16);
                float x1 = bfhi2f(((unsigned)((q >> 16) & 0xffffu)) << 16);
                float x2 = bfhi2f(((unsigned)((q >> 32) & 0xffffu)) << 16);
                float x3 = bfhi2f(((unsigned)((q >> 48) & 0xffffu)) << 16);
                sum += wp[i*4+0]*x0 + wp[i*4+1]*x1 + wp[i*4+2]*x2 + wp[i*4+3]*x3;
            }
            sum += __shfl_xor(sum, 16);
            sum += __shfl_xor(sum, 8);
            sum += __shfl_xor(sum, 4);
            sum += __shfl_xor(sum, 2);
            sum += __shfl_xor(sum, 1);
            if (lane32 == 0) {
                float* op = out + ((size_t)pb * T + (t - 2)) * 80 + po;
                *op += sum;
            }
        }
        // next step's input GEMM (read-only inputs, L2-cached)
        acc0[0] = (float4v){0.f, 0.f, 0.f, 0.f};
        acc0[1] = (float4v){0.f, 0.f, 0.f, 0.f};
        if (t + 1 < T) input_gemm(t + 1, acc0);
    }
}

extern "C" void kernel_launch(void* const* d_in, const int* in_sizes, int n_in,
                              void* d_out, int out_size, void* d_ws, size_t ws_size,
                              hipStream_t stream)
{
    const float* memory = (const float*)d_in[0];   // [32][1000][512]
    const float* y_mels = (const float*)d_in[1];   // [32][1000][80]
    const float* W1     = (const float*)d_in[2];   // [256][80]
    const float* W2     = (const float*)d_in[3];   // [256][256]
    const float* w_ih0  = (const float*)d_in[4];   // [4096][768]
    const float* w_hh0  = (const float*)d_in[5];   // [4096][1024]
    const float* b_ih0  = (const float*)d_in[6];
    const float* b_hh0  = (const float*)d_in[7];
    const float* w_ih1  = (const float*)d_in[8];   // [4096][1024]
    const float* w_hh1  = (const float*)d_in[9];   // [4096][1024]
    const float* b_ih1  = (const float*)d_in[10];
    const float* b_hh1  = (const float*)d_in[11];
    const float* Wp     = (const float*)d_in[12];  // [80][1536]
    const float* bp     = (const float*)d_in[13];  // [80]
    float* out = (float*)d_out;

    const int B = 32, T = 1000;

    float* ws = (float*)d_ws;
    float* p2 = ws;                                               // [T][B][256] fp32
    unsigned short* hb0 = (unsigned short*)(p2 + (size_t)T * B * 256); // [2][32][1024] bf16
    unsigned short* hb1 = hb0 + 2 * 32 * 1024;                         // [4][32][1024] bf16
    unsigned* bar = (unsigned*)(hb1 + 4 * 32 * 1024);                  // 16 KB barrier state

    // zero h buffers + barrier state (d_ws is poisoned 0xAA before every launch)
    hipMemsetAsync(hb0, 0,
                   (size_t)(2 + 4) * 32 * 1024 * sizeof(unsigned short) + 16384, stream);

    prenet_kernel<<<T * B, 256, 0, stream>>>(y_mels, W1, W2, p2, T);
    proj_mem_kernel<<<B * T, 128, 0, stream>>>(memory, Wp, bp, out, T);

    {
        int Tt = T;
        void* args[] = { (void*)&p2, (void*)&memory,
                         (void*)&w_ih0, (void*)&w_hh0, (void*)&b_ih0, (void*)&b_hh0,
                         (void*)&w_ih1, (void*)&w_hh1, (void*)&b_ih1, (void*)&b_hh1,
                         (void*)&Wp, (void*)&hb0, (void*)&hb1, (void*)&out, (void*)&bar, (void*)&Tt };
        hipLaunchCooperativeKernel((void*)fused_scan_mfma, dim3(256), dim3(512), args, 0, stream);
    }
}

// Round 8
// 13689.011 us; speedup vs baseline: 1.7000x; 1.4369x over previous
//
#include <hip/hip_runtime.h>
#include <cstddef>

typedef __attribute__((ext_vector_type(8))) short short8v;   // 8 bf16 = 4 VGPRs
typedef __attribute__((ext_vector_type(4))) float float4v;   // MFMA acc
typedef unsigned long long u64;

__device__ __forceinline__ float sigmoidf_(float x) {
    return 1.0f / (1.0f + __expf(-x));
}

__device__ __forceinline__ short f2bf(float f) {   // fp32 -> bf16 (RNE)
    union { float f; unsigned u; } v; v.f = f;
    unsigned r = (v.u + 0x7fffu + ((v.u >> 16) & 1u)) >> 16;
    return (short)r;
}

__device__ __forceinline__ float bfhi2f(unsigned bits_in_high) {  // bf16 bits at [31:16]
    union { unsigned u; float f; } v; v.u = bits_in_high; return v.f;
}

__device__ __forceinline__ short8v pack8(float4 a, float4 b) {
    short8v r;
    r[0] = f2bf(a.x); r[1] = f2bf(a.y); r[2] = f2bf(a.z); r[3] = f2bf(a.w);
    r[4] = f2bf(b.x); r[5] = f2bf(b.y); r[6] = f2bf(b.z); r[7] = f2bf(b.w);
    return r;
}

// coherent (agent-scope, L2-bypassing) 16B h-fragment load as two 8B atomics
__device__ __forceinline__ short8v load_h16(const unsigned short* p) {
    union { u64 q[2]; short8v v; } u;
    u.q[0] = __hip_atomic_load((const u64*)p,       __ATOMIC_RELAXED, __HIP_MEMORY_SCOPE_AGENT);
    u.q[1] = __hip_atomic_load((const u64*)(p + 4), __ATOMIC_RELAXED, __HIP_MEMORY_SCOPE_AGENT);
    return u.v;
}

#define FMA4(a4, w, x) \
    do { a4.x += (w).x*(x).x; a4.y += (w).y*(x).y; a4.z += (w).z*(x).z; a4.w += (w).w*(x).w; } while (0)

// ---------------- Prenet ----------------
__global__ __launch_bounds__(256) void prenet_kernel(
    const float* __restrict__ y_mels,   // [B][T][80]
    const float* __restrict__ W1,       // [256][80]
    const float* __restrict__ W2,       // [256][256]
    float* __restrict__ p2,             // [T][B][256]
    int T)
{
    const int rt = blockIdx.x;           // t*32 + b
    const int t = rt >> 5, b = rt & 31;
    const int j = threadIdx.x;           // 0..255
    __shared__ float prev[80];
    __shared__ float p1[256];
    if (j < 80) prev[j] = (t == 0) ? 0.0f : y_mels[((size_t)b * T + (t - 1)) * 80 + j];
    __syncthreads();
    float acc = 0.0f;
    const float* w1r = W1 + j * 80;
    #pragma unroll
    for (int k = 0; k < 80; k += 4) {
        float4 w = *(const float4*)(w1r + k);
        float4 x = *(const float4*)(&prev[k]);
        acc += w.x * x.x + w.y * x.y + w.z * x.z + w.w * x.w;
    }
    p1[j] = fmaxf(acc, 0.0f);
    __syncthreads();
    float4 a4 = make_float4(0.f, 0.f, 0.f, 0.f);
    const float* w2r = W2 + j * 256;
    #pragma unroll 8
    for (int k = 0; k < 256; k += 4) {
        float4 w = *(const float4*)(w2r + k);
        float4 x = *(const float4*)(&p1[k]);
        FMA4(a4, w, x);
    }
    p2[(size_t)rt * 256 + j] = fmaxf((a4.x + a4.y) + (a4.z + a4.w), 0.0f);
}

// ------------- Projection, memory part -------------
__global__ __launch_bounds__(128) void proj_mem_kernel(
    const float* __restrict__ memory, // [B][T][512]
    const float* __restrict__ Wp,     // [80][1536]
    const float* __restrict__ bp,     // [80]
    float* __restrict__ out,          // [B][T][80]
    int T)
{
    const int rt = blockIdx.x;
    const int tid = threadIdx.x;
    __shared__ float xm[512];
    for (int k = tid * 4; k < 512; k += 128 * 4)
        *(float4*)(&xm[k]) = *(const float4*)(memory + (size_t)rt * 512 + k);
    __syncthreads();
    if (tid < 80) {
        const float* wr = Wp + tid * 1536 + 1024;
        float4 a4 = make_float4(0.f, 0.f, 0.f, 0.f);
        #pragma unroll 8
        for (int k = 0; k < 512; k += 4) {
            float4 w = *(const float4*)(wr + k);
            float4 x = *(const float4*)(&xm[k]);
            FMA4(a4, w, x);
        }
        out[(size_t)rt * 80 + tid] = bp[tid] + (a4.x + a4.y) + (a4.z + a4.w);
    }
}

// ================= Persistent-weight MFMA scan =================
// 256 blocks x 512 threads, round-5 structure. h exchange uses agent-scope
// RELAXED atomics (per-access LLC coherence, L2 bypass). Barrier is FULLY
// RELAXED: h stores complete (vmcnt drain at syncthreads) before the arrive
// RMW issues; ordering flows through LLC serialization + data values. No
// acquire/release anywhere in the loop -> no per-step buffer_wbl2/buffer_inv,
// so read-only inputs (p2/memory/Wp) stay L2-resident across steps.
__global__ __launch_bounds__(512, 2) void fused_scan_mfma(
    const float* __restrict__ p2,     // [T][B][256]
    const float* __restrict__ memory, // [B][T][512]
    const float* __restrict__ w_ih0,  // [4096][768]
    const float* __restrict__ w_hh0,  // [4096][1024]
    const float* __restrict__ b_ih0,
    const float* __restrict__ b_hh0,
    const float* __restrict__ w_ih1,  // [4096][1024]
    const float* __restrict__ w_hh1,  // [4096][1024]
    const float* __restrict__ b_ih1,
    const float* __restrict__ b_hh1,
    const float* __restrict__ Wp,     // [80][1536]
    unsigned short* __restrict__ hb0, // [2][32][1024] bf16 (memset 0)
    unsigned short* __restrict__ hb1, // [4][32][1024] bf16 (memset 0)
    float* __restrict__ out,          // [B][T][80] (pre-filled with mem part)
    unsigned* __restrict__ bar,       // barrier state (memset 0)
    int T)
{
    const int bk  = blockIdx.x;
    const int tid = threadIdx.x;
    const int wave = tid >> 6;
    const int lane = tid & 63;
    const int col  = lane & 15;          // MFMA col (n) / A row (m)
    const int oct  = (lane >> 4) & 3;    // k-octet selector
    const int jcol = ((col >> 2) * 1024) + bk * 4 + (col & 3);

    // ---- persistent weight fragments ----
    const float* wr_i0 = w_ih0 + (size_t)jcol * 768;
    const float* wr_h0 = w_hh0 + (size_t)jcol * 1024;
    const float* wr_i1 = w_ih1 + (size_t)jcol * 1024;
    const float* wr_h1 = w_hh1 + (size_t)jcol * 1024;
    short8v wf_i0[3], wf_h0[4], wf_i1[4], wf_h1[4];
    #pragma unroll
    for (int s = 0; s < 3; ++s) {
        int k = wave * 96 + s * 32 + oct * 8;
        wf_i0[s] = pack8(*(const float4*)(wr_i0 + k), *(const float4*)(wr_i0 + k + 4));
    }
    #pragma unroll
    for (int s = 0; s < 4; ++s) {
        int k = wave * 128 + s * 32 + oct * 8;
        wf_h0[s] = pack8(*(const float4*)(wr_h0 + k), *(const float4*)(wr_h0 + k + 4));
        wf_i1[s] = pack8(*(const float4*)(wr_i1 + k), *(const float4*)(wr_i1 + k + 4));
        wf_h1[s] = pack8(*(const float4*)(wr_h1 + k), *(const float4*)(wr_h1 + k + 4));
    }

    // ---- LDS ----
    __shared__ float red[8][4][16][16];
    __shared__ float gl2[2][32][16];
    __shared__ float cst[2][32][4];
    __shared__ float bias_l[2][16];
    if (tid < 32) {
        int ly = tid >> 4, jl = tid & 15;
        int j = ((jl >> 2) * 1024) + bk * 4 + (jl & 3);
        bias_l[ly][jl] = ly ? (b_ih1[j] + b_hh1[j]) : (b_ih0[j] + b_hh0[j]);
    }
    if (tid < 256) cst[tid >> 7][(tid >> 2) & 31][tid & 3] = 0.0f;

    // ---- persistent projection weights ----
    const int gid = bk * 16 + (tid >> 5);
    const int lane32 = tid & 31;
    const int pb = gid / 80, po = gid - pb * 80;
    float wp[32];
    if (gid < 2560) {
        #pragma unroll
        for (int i = 0; i < 8; ++i) {
            float4 w = *(const float4*)(Wp + (size_t)po * 1536 + lane32 * 4 + i * 128);
            wp[i*4+0] = w.x; wp[i*4+1] = w.y; wp[i*4+2] = w.z; wp[i*4+3] = w.w;
        }
    }

    unsigned* grp_cnt  = bar + (bk >> 4) * 64;
    unsigned* root_cnt = bar + 1024;

    // ---- input GEMM lambda (x = [p2 | memory], K=768; normal cached loads) ----
    auto input_gemm = [&](int tt, float4v* acc) {
        #pragma unroll
        for (int s = 0; s < 3; ++s) {
            int kb = wave * 96 + s * 32;
            int kk = kb + oct * 8;
            short8v a0, a1;
            if (kb < 256) {
                const float* s0 = p2 + ((size_t)tt * 32 + col) * 256 + kk;
                const float* s1 = p2 + ((size_t)tt * 32 + col + 16) * 256 + kk;
                a0 = pack8(*(const float4*)s0, *(const float4*)(s0 + 4));
                a1 = pack8(*(const float4*)s1, *(const float4*)(s1 + 4));
            } else {
                const float* s0 = memory + ((size_t)col * T + tt) * 512 + (kk - 256);
                const float* s1 = memory + ((size_t)(col + 16) * T + tt) * 512 + (kk - 256);
                a0 = pack8(*(const float4*)s0, *(const float4*)(s0 + 4));
                a1 = pack8(*(const float4*)s1, *(const float4*)(s1 + 4));
            }
            acc[0] = __builtin_amdgcn_mfma_f32_16x16x32_bf16(a0, wf_i0[s], acc[0], 0, 0, 0);
            acc[1] = __builtin_amdgcn_mfma_f32_16x16x32_bf16(a1, wf_i0[s], acc[1], 0, 0, 0);
        }
    };

    __syncthreads();

    // prologue: input GEMM for t=0 (p2 ready by stream order)
    float4v acc0[2];
    acc0[0] = (float4v){0.f, 0.f, 0.f, 0.f};
    acc0[1] = (float4v){0.f, 0.f, 0.f, 0.f};
    if (T > 0) input_gemm(0, acc0);

    for (int t = 0; t <= T + 1; ++t) {
        // ---- wait for barrier t-1 (relaxed: h is per-access LLC-coherent) ----
        if (t > 0) {
            if (tid == 0) {
                while (__hip_atomic_load(root_cnt, __ATOMIC_RELAXED, __HIP_MEMORY_SCOPE_AGENT)
                       < 16u * (unsigned)t) { }
            }
            __syncthreads();
        }

        const bool doL0 = (t < T);
        const bool doL1 = (t >= 1) && (t <= T);
        float4v acc1[2];
        acc1[0] = (float4v){0.f, 0.f, 0.f, 0.f};
        acc1[1] = (float4v){0.f, 0.f, 0.f, 0.f};
        const unsigned short* h0prev  = hb0 + (size_t)((t + 1) & 1) * 32768;   // h0[t-1]
        const unsigned short* h1prev2 = hb1 + (size_t)((t - 2) & 3) * 32768;   // h1[t-2]

        // ---- h0[t-1]-driven GEMMs (coherent loads) ----
        if (doL0 || doL1) {
            #pragma unroll
            for (int s = 0; s < 4; ++s) {
                int kk = wave * 128 + s * 32 + oct * 8;
                short8v a0 = load_h16(h0prev + (size_t)col * 1024 + kk);
                short8v a1 = load_h16(h0prev + (size_t)(col + 16) * 1024 + kk);
                if (doL0) {
                    acc0[0] = __builtin_amdgcn_mfma_f32_16x16x32_bf16(a0, wf_h0[s], acc0[0], 0, 0, 0);
                    acc0[1] = __builtin_amdgcn_mfma_f32_16x16x32_bf16(a1, wf_h0[s], acc0[1], 0, 0, 0);
                }
                if (doL1) {
                    acc1[0] = __builtin_amdgcn_mfma_f32_16x16x32_bf16(a0, wf_i1[s], acc1[0], 0, 0, 0);
                    acc1[1] = __builtin_amdgcn_mfma_f32_16x16x32_bf16(a1, wf_i1[s], acc1[1], 0, 0, 0);
                }
            }
            if (doL1) {
                #pragma unroll
                for (int s = 0; s < 4; ++s) {
                    int kk = wave * 128 + s * 32 + oct * 8;
                    short8v a0 = load_h16(h1prev2 + (size_t)col * 1024 + kk);
                    short8v a1 = load_h16(h1prev2 + (size_t)(col + 16) * 1024 + kk);
                    acc1[0] = __builtin_amdgcn_mfma_f32_16x16x32_bf16(a0, wf_h1[s], acc1[0], 0, 0, 0);
                    acc1[1] = __builtin_amdgcn_mfma_f32_16x16x32_bf16(a1, wf_h1[s], acc1[1], 0, 0, 0);
                }
            }
        }
        // ---- cross-wave k-reduction ----
        if (doL0) {
            #pragma unroll
            for (int mt = 0; mt < 2; ++mt)
                #pragma unroll
                for (int r = 0; r < 4; ++r)
                    red[wave][mt][oct * 4 + r][col] = acc0[mt][r];
        }
        if (doL1) {
            #pragma unroll
            for (int mt = 0; mt < 2; ++mt)
                #pragma unroll
                for (int r = 0; r < 4; ++r)
                    red[wave][2 + mt][oct * 4 + r][col] = acc1[mt][r];
        }
        __syncthreads();
        #pragma unroll
        for (int e = tid; e < 1024; e += 512) {
            int tt = e >> 8, m = (e >> 4) & 15, n = e & 15;
            int ly = tt >> 1;
            if (ly ? doL1 : doL0) {
                float s = 0.f;
                #pragma unroll
                for (int w = 0; w < 8; ++w) s += red[w][tt][m][n];
                gl2[ly][(tt & 1) * 16 + m][n] = s + bias_l[ly][n];
            }
        }
        __syncthreads();
        // ---- activations (coherent 2B h stores) ----
        if (tid < 256) {
            int ly = tid >> 7, rem = tid & 127, bb = rem >> 2, cl = rem & 3;
            if (ly ? doL1 : doL0) {
                float gi = gl2[ly][bb][cl];
                float gf = gl2[ly][bb][4 + cl];
                float gg = gl2[ly][bb][8 + cl];
                float go = gl2[ly][bb][12 + cl];
                float c = sigmoidf_(gf) * cst[ly][bb][cl] + sigmoidf_(gi) * tanhf(gg);
                float h = sigmoidf_(go) * tanhf(c);
                cst[ly][bb][cl] = c;
                unsigned short hv = (unsigned short)f2bf(h);
                if (ly == 0)
                    __hip_atomic_store(hb0 + (size_t)(t & 1) * 32768 + bb * 1024 + bk * 4 + cl,
                                       hv, __ATOMIC_RELAXED, __HIP_MEMORY_SCOPE_AGENT);      // h0[t]
                else
                    __hip_atomic_store(hb1 + (size_t)((t - 1) & 3) * 32768 + bb * 1024 + bk * 4 + cl,
                                       hv, __ATOMIC_RELAXED, __HIP_MEMORY_SCOPE_AGENT);      // h1[t-1]
            }
        }
        __syncthreads();   // drains vmcnt: h stores COMPLETE at LLC before arrive

        // ---- arrive(t): fully relaxed (ordering via completed sc1 stores + LLC) ----
        if (tid == 0) {
            unsigned old = __hip_atomic_fetch_add(grp_cnt, 1u, __ATOMIC_RELAXED,
                                                  __HIP_MEMORY_SCOPE_AGENT);
            if (old == 16u * (unsigned)(t + 1) - 1u)
                __hip_atomic_fetch_add(root_cnt, 1u, __ATOMIC_RELAXED,
                                       __HIP_MEMORY_SCOPE_AGENT);
        }

        // ---- window: independent work overlapping barrier propagation ----
        if (t >= 2 && gid < 2560) {
            const unsigned short* hrow = h1prev2 + (size_t)pb * 1024;
            float sum = 0.f;
            #pragma unroll
            for (int i = 0; i < 8; ++i) {
                int k = lane32 * 4 + i * 128;
                u64 q = __hip_atomic_load((const u64*)(hrow + k),
                                          __ATOMIC_RELAXED, __HIP_MEMORY_SCOPE_AGENT);
                float x0 = bfhi2f(((unsigned)(q       & 0xffffu)) << 16);
                float x1 = bfhi2f(((unsigned)((q >> 16) & 0xffffu)) << 16);
                float x2 = bfhi2f(((unsigned)((q >> 32) & 0xffffu)) << 16);
                float x3 = bfhi2f(((unsigned)((q >> 48) & 0xffffu)) << 16);
                sum += wp[i*4+0]*x0 + wp[i*4+1]*x1 + wp[i*4+2]*x2 + wp[i*4+3]*x3;
            }
            sum += __shfl_xor(sum, 16);
            sum += __shfl_xor(sum, 8);
            sum += __shfl_xor(sum, 4);
            sum += __shfl_xor(sum, 2);
            sum += __shfl_xor(sum, 1);
            if (lane32 == 0) {
                float* op = out + ((size_t)pb * T + (t - 2)) * 80 + po;
                *op += sum;
            }
        }
        // next step's input GEMM (read-only inputs, L2-cached)
        acc0[0] = (float4v){0.f, 0.f, 0.f, 0.f};
        acc0[1] = (float4v){0.f, 0.f, 0.f, 0.f};
        if (t + 1 < T) input_gemm(t + 1, acc0);
    }
}

extern "C" void kernel_launch(void* const* d_in, const int* in_sizes, int n_in,
                              void* d_out, int out_size, void* d_ws, size_t ws_size,
                              hipStream_t stream)
{
    const float* memory = (const float*)d_in[0];   // [32][1000][512]
    const float* y_mels = (const float*)d_in[1];   // [32][1000][80]
    const float* W1     = (const float*)d_in[2];   // [256][80]
    const float* W2     = (const float*)d_in[3];   // [256][256]
    const float* w_ih0  = (const float*)d_in[4];   // [4096][768]
    const float* w_hh0  = (const float*)d_in[5];   // [4096][1024]
    const float* b_ih0  = (const float*)d_in[6];
    const float* b_hh0  = (const float*)d_in[7];
    const float* w_ih1  = (const float*)d_in[8];   // [4096][1024]
    const float* w_hh1  = (const float*)d_in[9];   // [4096][1024]
    const float* b_ih1  = (const float*)d_in[10];
    const float* b_hh1  = (const float*)d_in[11];
    const float* Wp     = (const float*)d_in[12];  // [80][1536]
    const float* bp     = (const float*)d_in[13];  // [80]
    float* out = (float*)d_out;

    const int B = 32, T = 1000;

    float* ws = (float*)d_ws;
    float* p2 = ws;                                               // [T][B][256] fp32
    unsigned short* hb0 = (unsigned short*)(p2 + (size_t)T * B * 256); // [2][32][1024] bf16
    unsigned short* hb1 = hb0 + 2 * 32 * 1024;                         // [4][32][1024] bf16
    unsigned* bar = (unsigned*)(hb1 + 4 * 32 * 1024);                  // 16 KB barrier state

    // zero h buffers + barrier state (d_ws is poisoned 0xAA before every launch)
    hipMemsetAsync(hb0, 0,
                   (size_t)(2 + 4) * 32 * 1024 * sizeof(unsigned short) + 16384, stream);

    prenet_kernel<<<T * B, 256, 0, stream>>>(y_mels, W1, W2, p2, T);
    proj_mem_kernel<<<B * T, 128, 0, stream>>>(memory, Wp, bp, out, T);

    {
        int Tt = T;
        void* args[] = { (void*)&p2, (void*)&memory,
                         (void*)&w_ih0, (void*)&w_hh0, (void*)&b_ih0, (void*)&b_hh0,
                         (void*)&w_ih1, (void*)&w_hh1, (void*)&b_ih1, (void*)&b_hh1,
                         (void*)&Wp, (void*)&hb0, (void*)&hb1, (void*)&out, (void*)&bar, (void*)&Tt };
        hipLaunchCooperativeKernel((void*)fused_scan_mfma, dim3(256), dim3(512), args, 0, stream);
    }
}